// Round 5
// baseline (210.781 us; speedup 1.0000x reference)
//
#include <hip/hip_runtime.h>
#include <float.h>

#define K_NN 10
#define BATCH 8
#define CIN 6
#define NPTS 4096
#define COUT 64
#define NSEG 8
#define SEGLEN (NPTS / NSEG)    // 512
#define CHUNK 16
#define NCHUNK (SEGLEN / CHUNK) // 32
#define CAP 32                  // survivor buffer (E[survivors]~12; exact fallback if overflow)
#define PPB 64                  // points per block in fused merge_feat
#define NEG_SLOPE 0.2f
#define BN_EPS 1e-5f

// ---- workspace layout (bytes) ----
// part[] aliases q[]: part planes for batch b are [80b,80b+80); q writes planes
// [80b,80b+64). Same batch => same column => same block => __syncthreads-ordered.
static constexpr size_t OFF_PTS2 = 0;                                                    // float4[8*4096] (ch3,4,5)
static constexpr size_t OFF_PTS  = OFF_PTS2 + (size_t)BATCH * NPTS * sizeof(float4);     // float4[8*4096] (xyz,norm)
static constexpr size_t OFF_Q    = OFF_PTS + (size_t)BATCH * NPTS * sizeof(float4);      // alias: q (80-plane stride) / part
static constexpr size_t SZ_Q     = (size_t)BATCH * NSEG * K_NN * NPTS * sizeof(int);     // 10.49 MB
static constexpr size_t OFF_ST   = OFF_Q + SZ_Q;                                         // double[27]
static constexpr size_t OFF_SS   = OFF_ST + 32 * sizeof(double);                         // float[128]

__device__ __forceinline__ float wave_sum(float v) {
#pragma unroll
    for (int m = 32; m >= 1; m >>= 1) v += __shfl_xor(v, m, 64);
    return v;
}
__device__ __forceinline__ float wave_max(float v) {
#pragma unroll
    for (int m = 32; m >= 1; m >>= 1) v = fmaxf(v, __shfl_xor(v, m, 64));
    return v;
}

// d' = 2*inner - ||c||^2 (drops per-query-constant ||q||^2; monotone shift, used
// consistently everywhere -> identical ordering). 4 VALU.
__device__ __forceinline__ float distp(float4 qp, float4 c) {
    return fmaf(2.0f, fmaf(qp.z, c.z, fmaf(qp.y, c.y, qp.x * c.x)), -c.w);
}

// lexicographic insert: key = (d desc, index asc). Processing-order independent,
// matches top_k tie semantics (earliest index wins on equal value).
__device__ __forceinline__ void lex_insert(float (&vals)[K_NN], int (&inds)[K_NN],
                                           float d, int m) {
    if (d > vals[K_NN - 1] || (d == vals[K_NN - 1] && m < inds[K_NN - 1])) {
        vals[K_NN - 1] = d;
        inds[K_NN - 1] = m;
#pragma unroll
        for (int t = K_NN - 1; t > 0; t--) {
            if (vals[t] > vals[t - 1] ||
                (vals[t] == vals[t - 1] && inds[t] < inds[t - 1])) {
                float tv = vals[t]; vals[t] = vals[t - 1]; vals[t - 1] = tv;
                int ti = inds[t]; inds[t] = inds[t - 1]; inds[t - 1] = ti;
            }
        }
    }
}

// ---- Kernel P: pack (x,y,z,||p||^2) and (c3,c4,c5) per point; block 0 zeroes stats ----
__global__ __launch_bounds__(256) void prep_pts(const float* __restrict__ x,
                                                float4* __restrict__ pts,
                                                float4* __restrict__ pts2,
                                                double* __restrict__ stats) {
    if (blockIdx.x == 0 && threadIdx.x < 27) stats[threadIdx.x] = 0.0;
    int t = blockIdx.x * 256 + threadIdx.x;   // 0..32767
    int b = t >> 12;
    int n = t & (NPTS - 1);
    const float* xb = x + (size_t)b * CIN * NPTS;
    float x0 = xb[n];
    float x1 = xb[NPTS + n];
    float x2 = xb[2 * NPTS + n];
    pts[t] = make_float4(x0, x1, x2, x0 * x0 + x1 * x1 + x2 * x2);
    pts2[t] = make_float4(xb[3 * NPTS + n], xb[4 * NPTS + n], xb[5 * NPTS + n], 0.f);
}

// ---- Kernel A1: per-segment exact top-10, chunk-max threshold scheme ----
__global__ __launch_bounds__(256) void knn_part(const float4* __restrict__ pts,
                                                int* __restrict__ part) {
    __shared__ unsigned int ssm[CAP * 256];   // u32 slots, [slot][tid]: bank=tid%32, free 2-way
    int b = blockIdx.y;
    int s = blockIdx.z;
    int n = blockIdx.x * 256 + threadIdx.x;
    const float4* p = pts + (size_t)b * NPTS;   // wave-uniform base -> scalar loads
    float4 qp = p[n];

    int m0 = s * SEGLEN;

    // ---- phase 1: threshold from chunk maxima ----
    float vals[K_NN];
#pragma unroll
    for (int j = 0; j < K_NN; j++) vals[j] = -FLT_MAX;

    for (int ch = 0; ch < NCHUNK; ch++) {
        float cmax = -FLT_MAX;
#pragma unroll
        for (int u = 0; u < CHUNK; u++) {
            float4 c = p[m0 + ch * CHUNK + u];
            cmax = fmaxf(cmax, distp(qp, c));
        }
        float t = cmax;
#pragma unroll
        for (int j = 0; j < K_NN; j++) {
            float hi = fmaxf(vals[j], t);
            t = fminf(vals[j], t);
            vals[j] = hi;
        }
    }
    float thr = vals[K_NN - 1];   // 10th-largest chunk max (<= exact v10)

    // ---- phase 2: collect survivors (d >= thr), branch-free ----
    int cnt = 0;
#pragma unroll 8
    for (int mm = 0; mm < SEGLEN; mm++) {
        float4 c = p[m0 + mm];
        float d = distp(qp, c);
        int slot = min(cnt, CAP - 1);
        ssm[slot * 256 + threadIdx.x] = (unsigned int)(m0 + mm);
        cnt += (d >= thr) ? 1 : 0;
    }

    // ---- drain: exact lex insert over survivors ----
    float fv[K_NN];
    int fi[K_NN];
#pragma unroll
    for (int j = 0; j < K_NN; j++) { fv[j] = -FLT_MAX; fi[j] = 0x7FFFFFFF; }

    if (cnt <= CAP) {
        for (int j = 0; j < cnt; j++) {
            int m = (int)ssm[j * 256 + threadIdx.x];
            float4 c = p[m];                    // L1-hot (segment = 8 KB)
            lex_insert(fv, fi, distp(qp, c), m);
        }
    } else {
        // exact fallback (essentially never taken; guarantees correctness)
        for (int mm = 0; mm < SEGLEN; mm++) {
            int m = m0 + mm;
            float4 c = p[m];
            lex_insert(fv, fi, distp(qp, c), m);
        }
    }

    // b-major plane layout: plane = b*80 + s*10 + j  (hazard-safe vs q aliasing)
    int* o = part + (((size_t)b * NSEG + s) * K_NN) * NPTS + n;
#pragma unroll
    for (int j = 0; j < K_NN; j++) o[(size_t)j * NPTS] = fi[j];
}

// ---- Kernel AB: fused merge (8 lists -> top-10) + gather + center + q + stats ----
// 4 threads per point: thread h merges segments {2h,2h+1}; partials exchanged via
// LDS; each thread computes channels [16h,16h+16). 512 blocks -> 2 waves/SIMD.
__global__ __launch_bounds__(256) void merge_feat(const float4* __restrict__ pts,
                                                  const float4* __restrict__ pts2,
                                                  const float* __restrict__ W,
                                                  const int* __restrict__ part,
                                                  float* __restrict__ q,
                                                  double* __restrict__ stats) {
    __shared__ float sW[COUT * CIN];
    __shared__ float ld[4][K_NN][PPB];
    __shared__ int   li[4][K_NN][PPB];
    __shared__ float sred[27];
    for (int i = threadIdx.x; i < COUT * CIN; i += 256) sW[i] = W[i];

    int b = blockIdx.y;
    int pt = threadIdx.x & (PPB - 1);
    int h = threadIdx.x >> 6;                 // 0..3 (= wave id)
    int n = blockIdx.x * PPB + pt;
    const float4* p = pts + (size_t)b * NPTS;
    const float4* p2 = pts2 + (size_t)b * NPTS;
    float4 qp = p[n];

    float vals[K_NN];
    int inds[K_NN];
#pragma unroll
    for (int j = 0; j < K_NN; j++) { vals[j] = -FLT_MAX; inds[j] = 0x7FFFFFFF; }

    // merge this thread's 2 segment lists (all part reads happen before the barrier)
#pragma unroll
    for (int ss = 0; ss < 2; ss++) {
        int s = h * 2 + ss;
        const int* pp = part + (((size_t)b * NSEG + s) * K_NN) * NPTS + n;
#pragma unroll
        for (int j = 0; j < K_NN; j++) {
            int m = pp[(size_t)j * NPTS];
            float4 c = p[m];                  // L2-resident (64 KB/batch)
            lex_insert(vals, inds, distp(qp, c), m);
        }
    }
#pragma unroll
    for (int j = 0; j < K_NN; j++) { ld[h][j][pt] = vals[j]; li[h][j][pt] = inds[j]; }
    __syncthreads();   // also orders all part reads before q writes (aliasing)

    // combine the other 3 partial lists (lex key -> order independent, exact)
#pragma unroll
    for (int oth = 1; oth < 4; oth++) {
        int hh = (h + oth) & 3;
#pragma unroll
        for (int j = 0; j < K_NN; j++)
            lex_insert(vals, inds, ld[hh][j][pt], li[hh][j][pt]);
    }

    // gather the 10 winners' 6 channels (L1/L2-hot) + center xyz
    float f[CIN][K_NN];
#pragma unroll
    for (int k = 0; k < K_NN; k++) {
        float4 c = p[inds[k]];
        float4 c2 = p2[inds[k]];
        f[0][k] = c.x; f[1][k] = c.y; f[2][k] = c.z;
        f[3][k] = c2.x; f[4][k] = c2.y; f[5][k] = c2.z;
    }
#pragma unroll
    for (int c = 0; c < 3; c++) {
        float s = 0.f;
#pragma unroll
        for (int k = 0; k < K_NN; k++) s += f[c][k];
        float m = s / 10.0f;
#pragma unroll
        for (int k = 0; k < K_NN; k++) f[c][k] = (f[c][k] - m) * 10.0f;
    }

    // q[b, plane o, n] for this thread's 16 channels (80-plane batch stride)
    float* qb = q + (size_t)b * 80 * NPTS + n;
#pragma unroll
    for (int oo = 0; oo < 16; oo++) {
        int o = h * 16 + oo;
        float w0 = sW[o * 6 + 0], w1 = sW[o * 6 + 1], w2 = sW[o * 6 + 2];
        float w3 = sW[o * 6 + 3], w4 = sW[o * 6 + 4], w5 = sW[o * 6 + 5];
        float mx = -FLT_MAX;
#pragma unroll
        for (int k = 0; k < K_NN; k++) {
            float y = w0 * f[0][k] + w1 * f[1][k] + w2 * f[2][k] +
                      w3 * f[3][k] + w4 * f[4][k] + w5 * f[5][k];
            mx = fmaxf(mx, y);
        }
        qb[(size_t)o * NPTS] = mx;
    }

    // stats from wave 0 only (h==0 covers each point exactly once)
    if (h == 0) {
        float s1[CIN];
#pragma unroll
        for (int c = 0; c < CIN; c++) {
            float s = 0.f;
#pragma unroll
            for (int k = 0; k < K_NN; k++) s += f[c][k];
            s1[c] = wave_sum(s);
        }
        float s2[21];
#pragma unroll
        for (int i = 0; i < 21; i++) s2[i] = 0.f;
#pragma unroll
        for (int k = 0; k < K_NN; k++) {
            int pp = 0;
#pragma unroll
            for (int c = 0; c < CIN; c++)
#pragma unroll
                for (int c2 = c; c2 < CIN; c2++) {
                    s2[pp] += f[c][k] * f[c2][k];
                    pp++;
                }
        }
#pragma unroll
        for (int i = 0; i < 21; i++) s2[i] = wave_sum(s2[i]);
        if (threadIdx.x == 0) {
#pragma unroll
            for (int c = 0; c < CIN; c++) sred[c] = s1[c];
#pragma unroll
            for (int i = 0; i < 21; i++) sred[6 + i] = s2[i];
        }
        // same-wave LDS write->read: ordered by program order + lgkmcnt
        if (threadIdx.x < 27) atomicAdd(&stats[threadIdx.x], (double)sred[threadIdx.x]);
    }
}

// ---- Kernel B2: fold moments through W -> per-channel scale/shift ----
__global__ void stats_kernel(const double* __restrict__ stats,
                             const float* __restrict__ W,
                             const float* __restrict__ gamma,
                             const float* __restrict__ beta,
                             float* __restrict__ ss) {
    int o = threadIdx.x;  // 64 threads
    const double minv = 1.0 / (double)((size_t)BATCH * NPTS * K_NN);
    double w[CIN];
#pragma unroll
    for (int c = 0; c < CIN; c++) w[c] = (double)W[o * CIN + c];
    double mu = 0.0;
#pragma unroll
    for (int c = 0; c < CIN; c++) mu += w[c] * stats[c];
    mu *= minv;
    double ey2 = 0.0;
    int p = 6;
#pragma unroll
    for (int c = 0; c < CIN; c++)
#pragma unroll
        for (int c2 = c; c2 < CIN; c2++) {
            double v = w[c] * w[c2] * stats[p];
            ey2 += (c2 == c) ? v : 2.0 * v;
            p++;
        }
    ey2 *= minv;
    double var = ey2 - mu * mu;
    float scale = gamma[o] * rsqrtf((float)var + BN_EPS);
    float shift = beta[o] - (float)mu * scale;
    ss[o] = scale;
    ss[COUT + o] = shift;
}

// ---- Kernel C: z = leaky(scale*q+shift); reduce max & mean over n ----
__global__ __launch_bounds__(256) void reduce_kernel(const float* __restrict__ q,
                                                     const float* __restrict__ ss,
                                                     float* __restrict__ out) {
    int o = blockIdx.x;
    int b = blockIdx.y;
    const float* qp = q + ((size_t)b * 80 + o) * NPTS;   // 80-plane batch stride
    float scale = ss[o], shift = ss[COUT + o];
    float mx = -FLT_MAX, sm = 0.f;
    for (int i = threadIdx.x; i < NPTS; i += 256) {
        float z = scale * qp[i] + shift;
        z = (z >= 0.f) ? z : NEG_SLOPE * z;
        mx = fmaxf(mx, z);
        sm += z;
    }
    mx = wave_max(mx);
    sm = wave_sum(sm);
    __shared__ float smx[4], ssm2[4];
    int wv = threadIdx.x >> 6;
    int ln = threadIdx.x & 63;
    if (ln == 0) { smx[wv] = mx; ssm2[wv] = sm; }
    __syncthreads();
    if (threadIdx.x == 0) {
        float m = fmaxf(fmaxf(smx[0], smx[1]), fmaxf(smx[2], smx[3]));
        float s = ssm2[0] + ssm2[1] + ssm2[2] + ssm2[3];
        out[b * 2 * COUT + o] = m;
        out[b * 2 * COUT + COUT + o] = s * (1.0f / (float)NPTS);
    }
}

extern "C" void kernel_launch(void* const* d_in, const int* in_sizes, int n_in,
                              void* d_out, int out_size, void* d_ws, size_t ws_size,
                              hipStream_t stream) {
    const float* x     = (const float*)d_in[0];
    const float* W     = (const float*)d_in[1];
    const float* gamma = (const float*)d_in[2];
    const float* beta  = (const float*)d_in[3];
    float* out = (float*)d_out;

    char* ws = (char*)d_ws;
    float4* pts2  = (float4*)(ws + OFF_PTS2);
    float4* pts   = (float4*)(ws + OFF_PTS);
    int*    part  = (int*)(ws + OFF_Q);     // aliases q region (hazard-safe, see layout note)
    float*  q     = (float*)(ws + OFF_Q);
    double* stats = (double*)(ws + OFF_ST);
    float*  ss    = (float*)(ws + OFF_SS);

    prep_pts<<<BATCH * NPTS / 256, 256, 0, stream>>>(x, pts, pts2, stats);
    knn_part<<<dim3(NPTS / 256, BATCH, NSEG), 256, 0, stream>>>(pts, part);
    merge_feat<<<dim3(NPTS / PPB, BATCH), 256, 0, stream>>>(pts, pts2, W, part, q, stats);
    stats_kernel<<<1, COUT, 0, stream>>>(stats, W, gamma, beta, ss);
    reduce_kernel<<<dim3(COUT, BATCH), 256, 0, stream>>>(q, ss, out);
}

// Round 6
// 200.754 us; speedup vs baseline: 1.0499x; 1.0499x over previous
//
#include <hip/hip_runtime.h>
#include <float.h>

#define K_NN 10
#define BATCH 8
#define CIN 6
#define NPTS 4096
#define COUT 64
#define NSEG 8
#define SEGLEN (NPTS / NSEG)    // 512
#define CHUNK 16
#define NCHUNK (SEGLEN / CHUNK) // 32
#define CAP 32                  // survivor buffer in knn_part (u16; E~12, exact fallback)
#define TPP 8                   // threads per point in merge_feat
#define PPB2 32                 // points per block in merge_feat (256 threads)
#define SCAP 80                 // survivor pool cap per point = worst case (8 lists x 10)
#define NEG_SLOPE 0.2f
#define BN_EPS 1e-5f

// ---- workspace layout (bytes) ----
// part[] aliases q[]: part planes for batch b are [80b,80b+80); q writes planes
// [80b,80b+64), same columns handled by the same block with a barrier between
// part reads and q writes; cross-block columns are disjoint.
static constexpr size_t OFF_PTS2 = 0;                                                    // float4[8*4096] (ch3,4,5)
static constexpr size_t OFF_PTS  = OFF_PTS2 + (size_t)BATCH * NPTS * sizeof(float4);     // float4[8*4096] (xyz,norm)
static constexpr size_t OFF_Q    = OFF_PTS + (size_t)BATCH * NPTS * sizeof(float4);      // alias: q (80-plane stride) / part
static constexpr size_t SZ_Q     = (size_t)BATCH * NSEG * K_NN * NPTS * sizeof(int);     // 10.49 MB
static constexpr size_t OFF_ST   = OFF_Q + SZ_Q;                                         // double[27]
static constexpr size_t OFF_SS   = OFF_ST + 32 * sizeof(double);                         // float[128]

__device__ __forceinline__ float wave_sum(float v) {
#pragma unroll
    for (int m = 32; m >= 1; m >>= 1) v += __shfl_xor(v, m, 64);
    return v;
}
__device__ __forceinline__ float wave_max(float v) {
#pragma unroll
    for (int m = 32; m >= 1; m >>= 1) v = fmaxf(v, __shfl_xor(v, m, 64));
    return v;
}

// d' = 2*inner - ||c||^2 (drops per-query-constant ||q||^2; monotone shift, used
// consistently everywhere -> identical ordering). 4 VALU. Deterministic fmaf ->
// bit-identical wherever recomputed.
__device__ __forceinline__ float distp(float4 qp, float4 c) {
    return fmaf(2.0f, fmaf(qp.z, c.z, fmaf(qp.y, c.y, qp.x * c.x)), -c.w);
}

// lexicographic insert: key = (d desc, index asc). Processing-order independent.
__device__ __forceinline__ void lex_insert(float (&vals)[K_NN], int (&inds)[K_NN],
                                           float d, int m) {
    if (d > vals[K_NN - 1] || (d == vals[K_NN - 1] && m < inds[K_NN - 1])) {
        vals[K_NN - 1] = d;
        inds[K_NN - 1] = m;
#pragma unroll
        for (int t = K_NN - 1; t > 0; t--) {
            if (vals[t] > vals[t - 1] ||
                (vals[t] == vals[t - 1] && inds[t] < inds[t - 1])) {
                float tv = vals[t]; vals[t] = vals[t - 1]; vals[t - 1] = tv;
                int ti = inds[t]; inds[t] = inds[t - 1]; inds[t - 1] = ti;
            }
        }
    }
}

// ---- Kernel P: pack (x,y,z,||p||^2) and (c3,c4,c5) per point; block 0 zeroes stats ----
__global__ __launch_bounds__(256) void prep_pts(const float* __restrict__ x,
                                                float4* __restrict__ pts,
                                                float4* __restrict__ pts2,
                                                double* __restrict__ stats) {
    if (blockIdx.x == 0 && threadIdx.x < 27) stats[threadIdx.x] = 0.0;
    int t = blockIdx.x * 256 + threadIdx.x;   // 0..32767
    int b = t >> 12;
    int n = t & (NPTS - 1);
    const float* xb = x + (size_t)b * CIN * NPTS;
    float x0 = xb[n];
    float x1 = xb[NPTS + n];
    float x2 = xb[2 * NPTS + n];
    pts[t] = make_float4(x0, x1, x2, x0 * x0 + x1 * x1 + x2 * x2);
    pts2[t] = make_float4(xb[3 * NPTS + n], xb[4 * NPTS + n], xb[5 * NPTS + n], 0.f);
}

// ---- Kernel A1: per-segment exact top-10 (R4 body: u16 survivors, strict->) ----
__global__ __launch_bounds__(256) void knn_part(const float4* __restrict__ pts,
                                                int* __restrict__ part) {
    __shared__ unsigned short ssm[CAP * 256];   // 16 KB
    int b = blockIdx.y;
    int s = blockIdx.z;
    int n = blockIdx.x * 256 + threadIdx.x;
    const float4* p = pts + (size_t)b * NPTS;   // wave-uniform base -> scalar loads
    float4 qp = p[n];

    int m0 = s * SEGLEN;

    // ---- phase 1: threshold from chunk maxima ----
    float vals[K_NN];
#pragma unroll
    for (int j = 0; j < K_NN; j++) vals[j] = -FLT_MAX;

    for (int ch = 0; ch < NCHUNK; ch++) {
        float cmax = -FLT_MAX;
#pragma unroll
        for (int u = 0; u < CHUNK; u++) {
            float4 c = p[m0 + ch * CHUNK + u];
            cmax = fmaxf(cmax, distp(qp, c));
        }
        float t = cmax;
#pragma unroll
        for (int j = 0; j < K_NN; j++) {
            float hi = fmaxf(vals[j], t);
            t = fminf(vals[j], t);
            vals[j] = hi;
        }
    }
    float thr = vals[K_NN - 1];   // 10th-largest chunk max (<= exact v10)

    // ---- phase 2: collect survivors (d >= thr), branch-free ----
    int cnt = 0;
#pragma unroll 8
    for (int mm = 0; mm < SEGLEN; mm++) {
        float4 c = p[m0 + mm];
        float d = distp(qp, c);
        int slot = min(cnt, CAP - 1);
        ssm[slot * 256 + threadIdx.x] = (unsigned short)(m0 + mm);
        cnt += (d >= thr) ? 1 : 0;
    }

    // ---- drain: exact strict-> insert over survivors (candidate order == index
    //      order -> earliest index wins ties; equals lex semantics) ----
    float fv[K_NN];
    int fi[K_NN];
#pragma unroll
    for (int j = 0; j < K_NN; j++) { fv[j] = -FLT_MAX; fi[j] = 0; }

    if (cnt <= CAP) {
        for (int j = 0; j < cnt; j++) {
            int m = ssm[j * 256 + threadIdx.x];
            float4 c = p[m];                    // L1-hot (segment = 8 KB)
            float d = distp(qp, c);
            if (d > fv[K_NN - 1]) {
                fv[K_NN - 1] = d;
                fi[K_NN - 1] = m;
#pragma unroll
                for (int t2 = K_NN - 1; t2 > 0; t2--) {
                    if (fv[t2] > fv[t2 - 1]) {
                        float tv = fv[t2]; fv[t2] = fv[t2 - 1]; fv[t2 - 1] = tv;
                        int ti = fi[t2]; fi[t2] = fi[t2 - 1]; fi[t2 - 1] = ti;
                    }
                }
            }
        }
    } else {
        // exact fallback (essentially never taken; guarantees correctness)
        for (int mm = 0; mm < SEGLEN; mm++) {
            int m = m0 + mm;
            float4 c = p[m];
            float d = distp(qp, c);
            if (d > fv[K_NN - 1]) {
                fv[K_NN - 1] = d;
                fi[K_NN - 1] = m;
#pragma unroll
                for (int t2 = K_NN - 1; t2 > 0; t2--) {
                    if (fv[t2] > fv[t2 - 1]) {
                        float tv = fv[t2]; fv[t2] = fv[t2 - 1]; fv[t2 - 1] = tv;
                        int ti = fi[t2]; fi[t2] = fi[t2 - 1]; fi[t2 - 1] = ti;
                    }
                }
            }
        }
    }

    // b-major plane layout (alias-safe vs q): plane = b*80 + s*10 + j, sorted desc
    int* o = part + (((size_t)b * NSEG + s) * K_NN) * NPTS + n;
#pragma unroll
    for (int j = 0; j < K_NN; j++) o[(size_t)j * NPTS] = fi[j];
}

// ---- Kernel AB: fused merge + gather + center + q + stats, 8 threads/point ----
// thread h owns segment h: 10 idx reads + 10 gathers (no duplication).
// t* = max_h (own 10th value) is a valid lower bound on the global 10th value
// (the argmax segment alone has 10 entries >= t*), so pooling all entries
// >= t* (max 80, pool cap 80: no overflow) provably contains the top-10.
// All 8 threads redundantly lex-merge the pool (order-independent, exact).
__global__ __launch_bounds__(256) void merge_feat(const float4* __restrict__ pts,
                                                  const float4* __restrict__ pts2,
                                                  const float* __restrict__ W,
                                                  const int* __restrict__ part,
                                                  float* __restrict__ q,
                                                  double* __restrict__ stats) {
    __shared__ float sW[COUT * CIN];                 // 1.5 KB
    __shared__ float sdv[PPB2][SCAP];                // 10 KB
    __shared__ unsigned short smv[PPB2][SCAP];       // 5 KB
    __shared__ int scnt[PPB2];
    __shared__ float sf[CIN][K_NN][PPB2];            // 7.5 KB
    __shared__ float sred[4][27];

    int tid = threadIdx.x;
    int h = tid & (TPP - 1);       // segment / channel-group owner
    int pt = tid >> 3;             // 0..31
    int b = blockIdx.y;
    int n = blockIdx.x * PPB2 + pt;

    for (int i = tid; i < COUT * CIN; i += 256) sW[i] = W[i];
    if (h == 0) scnt[pt] = 0;
    __syncthreads();

    const float4* p = pts + (size_t)b * NPTS;
    const float4* p2 = pts2 + (size_t)b * NPTS;
    float4 qp = p[n];

    // my segment's sorted list: indices + recomputed distances (bit-identical)
    const int* pp = part + (((size_t)b * NSEG + h) * K_NN) * NPTS + n;
    int ms[K_NN];
#pragma unroll
    for (int j = 0; j < K_NN; j++) ms[j] = pp[(size_t)j * NPTS];
    float ds[K_NN];
#pragma unroll
    for (int j = 0; j < K_NN; j++) ds[j] = distp(qp, p[ms[j]]);

    // t* = max over the point's 8 threads of own 10th value (lanes pt*8+h: group
    // of 8 contiguous lanes -> shfl_xor 1,2,4 stays in group)
    float t = ds[K_NN - 1];
    t = fmaxf(t, __shfl_xor(t, 1, 64));
    t = fmaxf(t, __shfl_xor(t, 2, 64));
    t = fmaxf(t, __shfl_xor(t, 4, 64));

    // emit my entries >= t* into the point's pool (sorted desc -> break early)
#pragma unroll
    for (int j = 0; j < K_NN; j++) {
        if (ds[j] >= t) {
            int slot = atomicAdd(&scnt[pt], 1);   // slot < 80 always
            sdv[pt][slot] = ds[j];
            smv[pt][slot] = (unsigned short)ms[j];
        } else break;
    }
    __syncthreads();   // pool complete; also orders all part reads before q writes

    // redundant exact lex-merge of the pool (same multiset -> same result)
    int cnt = scnt[pt];
    float fv[K_NN];
    int fi[K_NN];
#pragma unroll
    for (int j = 0; j < K_NN; j++) { fv[j] = -FLT_MAX; fi[j] = 0x7FFFFFFF; }
    for (int i2 = 0; i2 < cnt; i2++)
        lex_insert(fv, fi, sdv[pt][i2], (int)smv[pt][i2]);

    // winner feature gather, split across threads: thread h does k = h, h+8
    for (int k = h; k < K_NN; k += TPP) {
        float4 c = p[fi[k]];
        float4 c2 = p2[fi[k]];
        sf[0][k][pt] = c.x; sf[1][k][pt] = c.y; sf[2][k][pt] = c.z;
        sf[3][k][pt] = c2.x; sf[4][k][pt] = c2.y; sf[5][k][pt] = c2.z;
    }
    __syncthreads();

    // xyz means (cheap, redundant per thread), centered feature read
    float mean[3];
#pragma unroll
    for (int c = 0; c < 3; c++) {
        float s = 0.f;
#pragma unroll
        for (int k = 0; k < K_NN; k++) s += sf[c][k][pt];
        mean[c] = s / 10.0f;
    }
    float f[CIN][K_NN];
#pragma unroll
    for (int c = 0; c < CIN; c++)
#pragma unroll
        for (int k = 0; k < K_NN; k++) {
            float v = sf[c][k][pt];
            f[c][k] = (c < 3) ? (v - mean[c]) * 10.0f : v;
        }

    // channels [8h, 8h+8): q[b, plane o, n] (80-plane batch stride)
    float* qb = q + (size_t)b * 80 * NPTS + n;
#pragma unroll
    for (int oo = 0; oo < 8; oo++) {
        int o = h * 8 + oo;
        float w0 = sW[o * 6 + 0], w1 = sW[o * 6 + 1], w2 = sW[o * 6 + 2];
        float w3 = sW[o * 6 + 3], w4 = sW[o * 6 + 4], w5 = sW[o * 6 + 5];
        float mx = -FLT_MAX;
#pragma unroll
        for (int k = 0; k < K_NN; k++) {
            float y = w0 * f[0][k] + w1 * f[1][k] + w2 * f[2][k] +
                      w3 * f[3][k] + w4 * f[4][k] + w5 * f[5][k];
            mx = fmaxf(mx, y);
        }
        qb[(size_t)o * NPTS] = mx;
    }

    // stats: h==0 lanes contribute their point, others 0; wave+block reduce
    float s1[CIN];
    float s2[21];
#pragma unroll
    for (int c = 0; c < CIN; c++) s1[c] = 0.f;
#pragma unroll
    for (int i = 0; i < 21; i++) s2[i] = 0.f;
    if (h == 0) {
#pragma unroll
        for (int c = 0; c < CIN; c++) {
            float s = 0.f;
#pragma unroll
            for (int k = 0; k < K_NN; k++) s += f[c][k];
            s1[c] = s;
        }
#pragma unroll
        for (int k = 0; k < K_NN; k++) {
            int pp2 = 0;
#pragma unroll
            for (int c = 0; c < CIN; c++)
#pragma unroll
                for (int c2 = c; c2 < CIN; c2++) {
                    s2[pp2] += f[c][k] * f[c2][k];
                    pp2++;
                }
        }
    }
#pragma unroll
    for (int c = 0; c < CIN; c++) s1[c] = wave_sum(s1[c]);
#pragma unroll
    for (int i = 0; i < 21; i++) s2[i] = wave_sum(s2[i]);

    int wv = tid >> 6;
    int ln = tid & 63;
    if (ln == 0) {
#pragma unroll
        for (int c = 0; c < CIN; c++) sred[wv][c] = s1[c];
#pragma unroll
        for (int i = 0; i < 21; i++) sred[wv][6 + i] = s2[i];
    }
    __syncthreads();
    if (tid < 27) {
        float tt = sred[0][tid] + sred[1][tid] + sred[2][tid] + sred[3][tid];
        atomicAdd(&stats[tid], (double)tt);
    }
}

// ---- Kernel B2: fold moments through W -> per-channel scale/shift ----
__global__ void stats_kernel(const double* __restrict__ stats,
                             const float* __restrict__ W,
                             const float* __restrict__ gamma,
                             const float* __restrict__ beta,
                             float* __restrict__ ss) {
    int o = threadIdx.x;  // 64 threads
    const double minv = 1.0 / (double)((size_t)BATCH * NPTS * K_NN);
    double w[CIN];
#pragma unroll
    for (int c = 0; c < CIN; c++) w[c] = (double)W[o * CIN + c];
    double mu = 0.0;
#pragma unroll
    for (int c = 0; c < CIN; c++) mu += w[c] * stats[c];
    mu *= minv;
    double ey2 = 0.0;
    int p = 6;
#pragma unroll
    for (int c = 0; c < CIN; c++)
#pragma unroll
        for (int c2 = c; c2 < CIN; c2++) {
            double v = w[c] * w[c2] * stats[p];
            ey2 += (c2 == c) ? v : 2.0 * v;
            p++;
        }
    ey2 *= minv;
    double var = ey2 - mu * mu;
    float scale = gamma[o] * rsqrtf((float)var + BN_EPS);
    float shift = beta[o] - (float)mu * scale;
    ss[o] = scale;
    ss[COUT + o] = shift;
}

// ---- Kernel C: z = leaky(scale*q+shift); reduce max & mean over n ----
__global__ __launch_bounds__(256) void reduce_kernel(const float* __restrict__ q,
                                                     const float* __restrict__ ss,
                                                     float* __restrict__ out) {
    int o = blockIdx.x;
    int b = blockIdx.y;
    const float* qp = q + ((size_t)b * 80 + o) * NPTS;   // 80-plane batch stride
    float scale = ss[o], shift = ss[COUT + o];
    float mx = -FLT_MAX, sm = 0.f;
    for (int i = threadIdx.x; i < NPTS; i += 256) {
        float z = scale * qp[i] + shift;
        z = (z >= 0.f) ? z : NEG_SLOPE * z;
        mx = fmaxf(mx, z);
        sm += z;
    }
    mx = wave_max(mx);
    sm = wave_sum(sm);
    __shared__ float smx[4], ssm2[4];
    int wv = threadIdx.x >> 6;
    int ln = threadIdx.x & 63;
    if (ln == 0) { smx[wv] = mx; ssm2[wv] = sm; }
    __syncthreads();
    if (threadIdx.x == 0) {
        float m = fmaxf(fmaxf(smx[0], smx[1]), fmaxf(smx[2], smx[3]));
        float s = ssm2[0] + ssm2[1] + ssm2[2] + ssm2[3];
        out[b * 2 * COUT + o] = m;
        out[b * 2 * COUT + COUT + o] = s * (1.0f / (float)NPTS);
    }
}

extern "C" void kernel_launch(void* const* d_in, const int* in_sizes, int n_in,
                              void* d_out, int out_size, void* d_ws, size_t ws_size,
                              hipStream_t stream) {
    const float* x     = (const float*)d_in[0];
    const float* W     = (const float*)d_in[1];
    const float* gamma = (const float*)d_in[2];
    const float* beta  = (const float*)d_in[3];
    float* out = (float*)d_out;

    char* ws = (char*)d_ws;
    float4* pts2  = (float4*)(ws + OFF_PTS2);
    float4* pts   = (float4*)(ws + OFF_PTS);
    int*    part  = (int*)(ws + OFF_Q);     // aliases q region (alias-safe, see layout note)
    float*  q     = (float*)(ws + OFF_Q);
    double* stats = (double*)(ws + OFF_ST);
    float*  ss    = (float*)(ws + OFF_SS);

    prep_pts<<<BATCH * NPTS / 256, 256, 0, stream>>>(x, pts, pts2, stats);
    knn_part<<<dim3(NPTS / 256, BATCH, NSEG), 256, 0, stream>>>(pts, part);
    merge_feat<<<dim3(NPTS / PPB2, BATCH), 256, 0, stream>>>(pts, pts2, W, part, q, stats);
    stats_kernel<<<1, COUT, 0, stream>>>(stats, W, gamma, beta, ss);
    reduce_kernel<<<dim3(COUT, BATCH), 256, 0, stream>>>(q, ss, out);
}